// Round 4
// baseline (1694.208 us; speedup 1.0000x reference)
//
#include <hip/hip_runtime.h>
#include <stdint.h>

#define GAS __attribute__((address_space(1)))
#define LAS __attribute__((address_space(3)))

typedef __attribute__((ext_vector_type(8))) short short8;
typedef __attribute__((ext_vector_type(4))) float float4v;
typedef __attribute__((ext_vector_type(4))) unsigned int uint4v;

__device__ __forceinline__ unsigned short f2bf(float f) {
  union { float f; unsigned int u; } v; v.f = f;
  unsigned int r = v.u + 0x7fffu + ((v.u >> 16) & 1u);
  return (unsigned short)(r >> 16);
}

__device__ __forceinline__ void async_g2l16(const void* g, void* l) {
  __builtin_amdgcn_global_load_lds((const GAS unsigned int*)g,
                                   (LAS unsigned int*)l, 16, 0, 0);
}

// Full VMEM drain before s_barrier: guarantees in-flight global_load_lds
// (LDS-DMA) have landed, independent of compiler DMA tracking (R1 bug fix).
__device__ __forceinline__ void vmem_drain() {
  asm volatile("s_waitcnt vmcnt(0)" ::: "memory");
}

// ---- Kernel A: normalize y -> bf16 fragment-major [t][og*2+cb][lane][8] ----
// For t=dy*16+dx: fragment g=(og*2+cb) is 1KB; lane = q*16 + (o&15) holds
// o = og*16+(o&15), c = cb*32 + q*8 + j  (the 16x16x32 B-operand mapping).
__global__ void knorm_y(const float* __restrict__ y, unsigned short* __restrict__ y_t2) {
  int o = blockIdx.x;
  int tid = threadIdx.x;
  const float* yo = y + o * 16384;
  float s = 0.f;
  for (int idx = tid; idx < 16384; idx += 256) { float v = yo[idx]; s += v * v; }
  for (int off = 32; off; off >>= 1) s += __shfl_down(s, off, 64);
  __shared__ float red[4];
  if ((tid & 63) == 0) red[tid >> 6] = s;
  __syncthreads();
  float rn = 1.0f / sqrtf(red[0] + red[1] + red[2] + red[3]);
  int og = o >> 4, ol = o & 15;
  for (int idx = tid; idx < 16384; idx += 256) {
    int c = idx >> 8, dy = (idx >> 4) & 15, dx = idx & 15;
    int t = dy * 16 + dx;
    int cb = c >> 5, q = (c >> 3) & 3, j = c & 7;
    size_t dst = (size_t)t * 4096 + (size_t)(og * 2 + cb) * 512 + (q * 16 + ol) * 8 + j;
    y_t2[dst] = f2bf(yo[idx] * rn);
  }
}

// ------- Kernel B: x (NCHW f32) -> x_t bf16 [n][h][w][c] swizzled, + s -----
__global__ void ktrans_x(const float* __restrict__ x, unsigned short* __restrict__ x_t,
                         float* __restrict__ s) {
  int h = blockIdx.x, n = blockIdx.y;
  int tid = threadIdx.x;
  __shared__ __align__(16) unsigned short tb[8192];
  __shared__ float sb[256];
  const float* xb = x + ((size_t)n * 64) * 16384 + h * 128;
  int w = tid & 127, half = tid >> 7;
  float acc = 0.f;
#pragma unroll
  for (int cs = 0; cs < 4; ++cs) {
    short8 tmp;
#pragma unroll
    for (int j = 0; j < 8; ++j) {
      int c = half * 32 + cs * 8 + j;
      float v = xb[(size_t)c * 16384 + w];
      tmp[j] = (short)f2bf(v);
      acc += v * v;
    }
    int chunk = (half * 4 + cs) ^ (w & 7);
    *(short8*)(tb + w * 64 + chunk * 8) = tmp;
  }
  sb[tid] = acc;
  __syncthreads();
  uint4v* dst = (uint4v*)(x_t + ((size_t)(n * 128 + h)) * 8192);
  const uint4v* src = (const uint4v*)tb;
  for (int idx = tid; idx < 1024; idx += 256) dst[idx] = src[idx];
  if (tid < 128) s[((size_t)(n * 128 + h)) * 128 + tid] = sb[tid] + sb[tid + 128];
}

// ---------------- Kernel D: separable 16x16 box sum of s -> 1/sqrt --------
__global__ void knorm_x(const float* __restrict__ s, float* __restrict__ invn) {
  int i = blockIdx.x, n = blockIdx.y;
  int tid = threadIdx.x;  // 128
  __shared__ float colsum[128];
  const float* sp = s + ((size_t)(n * 128 + i)) * 128;
  float a = 0.f;
#pragma unroll
  for (int dy = 0; dy < 16; ++dy) a += sp[dy * 128 + tid];
  colsum[tid] = a;
  __syncthreads();
  if (tid < 113) {
    float acc = 0.f;
#pragma unroll
    for (int dx = 0; dx < 16; ++dx) acc += colsum[tid + dx];
    invn[((size_t)n * 113 + i) * 113 + tid] = 1.0f / sqrtf(acc);
  }
}

// ---------------- Kernel E: main implicit-GEMM conv -----------------------
// block = (row i, image n), 128 threads = 2 waves. Wave tile M64 x N64:
// A-LDS duplication 1x (16 KB/slot, ~53 B/cyc demand vs 85 achievable),
// B duplication 2x but identical addresses across the 2 waves -> L1 dedup.
// Per dx per wave: 8 ds_read_b128 + 8 global b128 (B) + 32 MFMA (4:1).
__launch_bounds__(128, 2)
__global__ void kconv(const unsigned short* __restrict__ x_t,
                      const unsigned short* __restrict__ y_t2,
                      const float* __restrict__ invn,
                      float* __restrict__ out) {
  int i = blockIdx.x;
  int n = blockIdx.y;
  int tid = threadIdx.x;
  int lane = tid & 63, wave = tid >> 6;
  int lane15 = lane & 15, q = lane >> 4;

  __shared__ __align__(16) char smem[32768];
  char* const A0 = smem;
  char* const A1 = smem + 16384;

  const char* xrow0 = (const char*)(x_t + ((size_t)(n * 128 + i)) * 8192);

  auto stageA = [&](int dy, char* buf) {
    const char* src = xrow0 + (size_t)dy * 16384;
#pragma unroll
    for (int it = 0; it < 8; ++it) {
      int chunk = it * 128 + wave * 64;  // wave-uniform LDS base
      async_g2l16(src + (chunk + lane) * 16, buf + chunk * 16);
    }
  };

  const short8* ybase = (const short8*)y_t2 + lane;
  auto loadB = [&](int t, short8 bf[4][2]) {
    const short8* p = ybase + (size_t)t * 512;  // 512 short8 per t
#pragma unroll
    for (int nt = 0; nt < 4; ++nt)
#pragma unroll
      for (int cb = 0; cb < 2; ++cb) bf[nt][cb] = p[(nt * 2 + cb) * 64];
  };

  float4v acc[4][4];
#pragma unroll
  for (int mt = 0; mt < 4; ++mt)
#pragma unroll
    for (int nt = 0; nt < 4; ++nt) acc[mt][nt] = (float4v){0.f, 0.f, 0.f, 0.f};

  int abase[4];
#pragma unroll
  for (int mt = 0; mt < 4; ++mt) abase[mt] = (wave * 64 + mt * 16 + lane15) * 128;

  stageA(0, A0);
  short8 bc[4][2];
  loadB(0, bc);
  vmem_drain();
  __syncthreads();

#pragma unroll 1
  for (int dy = 0; dy < 16; ++dy) {
    char* Ab = (dy & 1) ? A1 : A0;
    if (dy < 15) stageA(dy + 1, (dy & 1) ? A0 : A1);
#pragma unroll
    for (int dx = 0; dx < 16; ++dx) {
      int t = dy * 16 + dx;
      short8 bn[4][2];
      if (t < 255) loadB(t + 1, bn);
      int xr = (lane15 + dx) & 7;
#pragma unroll
      for (int cb = 0; cb < 2; ++cb) {
        int aoff = dx * 128 + (((q + cb * 4) ^ xr) << 4);
#pragma unroll
        for (int mt = 0; mt < 4; ++mt) {
          short8 a = *(const short8*)(Ab + abase[mt] + aoff);
#pragma unroll
          for (int nt = 0; nt < 4; ++nt)
            acc[mt][nt] = __builtin_amdgcn_mfma_f32_16x16x32_bf16(a, bc[nt][cb], acc[mt][nt], 0, 0, 0);
        }
      }
      if (t < 255) {
#pragma unroll
        for (int nt = 0; nt < 4; ++nt)
#pragma unroll
          for (int cb = 0; cb < 2; ++cb) bc[nt][cb] = bn[nt][cb];
      }
    }
    // Drain LDS-DMA (stageA(dy+1)) before the buffer-swap barrier (R1 bug).
    vmem_drain();
    __syncthreads();
  }

  // Epilogue: two-pass (o-halves) transpose through LDS, fuse invn + relu.
  float* cs = (float*)smem;        // 32 x 132 floats = 16896 B
  float* ivs = cs + 4224;          // 128 floats
  const float* ivp = invn + ((size_t)n * 113 + i) * 113;
  ivs[tid] = (tid < 113) ? ivp[tid] : 0.f;
  float* op = out + (size_t)n * 64 * 12769 + (size_t)i * 113;
#pragma unroll 1
  for (int p = 0; p < 2; ++p) {
#pragma unroll
    for (int mt = 0; mt < 4; ++mt)
#pragma unroll
      for (int ntl = 0; ntl < 2; ++ntl) {
        int nt = p * 2 + ntl;
        int row = ntl * 16 + lane15;          // o - p*32
        int j0 = wave * 64 + mt * 16 + q * 4;
        *(float4v*)(cs + row * 132 + j0) = acc[mt][nt];
      }
    __syncthreads();
    for (int idx = tid; idx < 4096; idx += 128) {
      int o2 = idx >> 7, j = idx & 127;
      if (j < 113) {
        float v = cs[o2 * 132 + j] * ivs[j];
        op[(size_t)(p * 32 + o2) * 12769 + j] = fmaxf(v, 0.f);
      }
    }
    __syncthreads();
  }
}

extern "C" void kernel_launch(void* const* d_in, const int* in_sizes, int n_in,
                              void* d_out, int out_size, void* d_ws, size_t ws_size,
                              hipStream_t stream) {
  const float* x = (const float*)d_in[0];
  const float* y = (const float*)d_in[1];
  float* out = (float*)d_out;
  char* ws = (char*)d_ws;
  unsigned short* x_t = (unsigned short*)ws;                 // 33,554,432 B
  unsigned short* y_t2 = (unsigned short*)(ws + 33554432);   //  2,097,152 B
  float* s = (float*)(ws + 35651584);                        //  1,048,576 B
  float* invn = (float*)(ws + 36700160);                     //    817,216 B

  hipLaunchKernelGGL(knorm_y, dim3(64), dim3(256), 0, stream, y, y_t2);
  hipLaunchKernelGGL(ktrans_x, dim3(128, 16), dim3(256), 0, stream, x, x_t, s);
  hipLaunchKernelGGL(knorm_x, dim3(113, 16), dim3(128), 0, stream, s, invn);
  hipLaunchKernelGGL(kconv, dim3(113, 16), dim3(128), 0, stream, x_t, y_t2, invn, out);
}

// Round 5
// 701.182 us; speedup vs baseline: 2.4162x; 2.4162x over previous
//
#include <hip/hip_runtime.h>
#include <stdint.h>

#define GAS __attribute__((address_space(1)))
#define LAS __attribute__((address_space(3)))

typedef __attribute__((ext_vector_type(8))) short short8;
typedef __attribute__((ext_vector_type(4))) float float4v;
typedef __attribute__((ext_vector_type(4))) unsigned int uint4v;

__device__ __forceinline__ unsigned short f2bf(float f) {
  union { float f; unsigned int u; } v; v.f = f;
  unsigned int r = v.u + 0x7fffu + ((v.u >> 16) & 1u);
  return (unsigned short)(r >> 16);
}

__device__ __forceinline__ void async_g2l16(const void* g, void* l) {
  __builtin_amdgcn_global_load_lds((const GAS unsigned int*)g,
                                   (LAS unsigned int*)l, 16, 0, 0);
}

// Full VMEM drain before s_barrier: guarantees in-flight global_load_lds
// (LDS-DMA) have landed, independent of compiler DMA tracking (R1 bug fix).
__device__ __forceinline__ void vmem_drain() {
  asm volatile("s_waitcnt vmcnt(0)" ::: "memory");
}

// ---- Kernel A: normalize y -> bf16 fragment-major [t][og*2+cb][lane][8] ----
// For t=dy*16+dx: fragment g=(og*2+cb) is 1KB; lane = q*16 + (o&15) holds
// o = og*16+(o&15), c = cb*32 + q*8 + j  (the 16x16x32 B-operand mapping).
__global__ void knorm_y(const float* __restrict__ y, unsigned short* __restrict__ y_t2) {
  int o = blockIdx.x;
  int tid = threadIdx.x;
  const float* yo = y + o * 16384;
  float s = 0.f;
  for (int idx = tid; idx < 16384; idx += 256) { float v = yo[idx]; s += v * v; }
  for (int off = 32; off; off >>= 1) s += __shfl_down(s, off, 64);
  __shared__ float red[4];
  if ((tid & 63) == 0) red[tid >> 6] = s;
  __syncthreads();
  float rn = 1.0f / sqrtf(red[0] + red[1] + red[2] + red[3]);
  int og = o >> 4, ol = o & 15;
  for (int idx = tid; idx < 16384; idx += 256) {
    int c = idx >> 8, dy = (idx >> 4) & 15, dx = idx & 15;
    int t = dy * 16 + dx;
    int cb = c >> 5, q = (c >> 3) & 3, j = c & 7;
    size_t dst = (size_t)t * 4096 + (size_t)(og * 2 + cb) * 512 + (q * 16 + ol) * 8 + j;
    y_t2[dst] = f2bf(yo[idx] * rn);
  }
}

// ------- Kernel B: x (NCHW f32) -> x_t bf16 [n][h][w][c] swizzled, + s -----
__global__ void ktrans_x(const float* __restrict__ x, unsigned short* __restrict__ x_t,
                         float* __restrict__ s) {
  int h = blockIdx.x, n = blockIdx.y;
  int tid = threadIdx.x;
  __shared__ __align__(16) unsigned short tb[8192];
  __shared__ float sb[256];
  const float* xb = x + ((size_t)n * 64) * 16384 + h * 128;
  int w = tid & 127, half = tid >> 7;
  float acc = 0.f;
#pragma unroll
  for (int cs = 0; cs < 4; ++cs) {
    short8 tmp;
#pragma unroll
    for (int j = 0; j < 8; ++j) {
      int c = half * 32 + cs * 8 + j;
      float v = xb[(size_t)c * 16384 + w];
      tmp[j] = (short)f2bf(v);
      acc += v * v;
    }
    int chunk = (half * 4 + cs) ^ (w & 7);
    *(short8*)(tb + w * 64 + chunk * 8) = tmp;
  }
  sb[tid] = acc;
  __syncthreads();
  uint4v* dst = (uint4v*)(x_t + ((size_t)(n * 128 + h)) * 8192);
  const uint4v* src = (const uint4v*)tb;
  for (int idx = tid; idx < 1024; idx += 256) dst[idx] = src[idx];
  if (tid < 128) s[((size_t)(n * 128 + h)) * 128 + tid] = sb[tid] + sb[tid + 128];
}

// ---------------- Kernel D: separable 16x16 box sum of s -> 1/sqrt --------
__global__ void knorm_x(const float* __restrict__ s, float* __restrict__ invn) {
  int i = blockIdx.x, n = blockIdx.y;
  int tid = threadIdx.x;  // 128
  __shared__ float colsum[128];
  const float* sp = s + ((size_t)(n * 128 + i)) * 128;
  float a = 0.f;
#pragma unroll
  for (int dy = 0; dy < 16; ++dy) a += sp[dy * 128 + tid];
  colsum[tid] = a;
  __syncthreads();
  if (tid < 113) {
    float acc = 0.f;
#pragma unroll
    for (int dx = 0; dx < 16; ++dx) acc += colsum[tid + dx];
    invn[((size_t)n * 113 + i) * 113 + tid] = 1.0f / sqrtf(acc);
  }
}

// ---------------- Kernel E: main implicit-GEMM conv -----------------------
// block = (row i, image n), 128 threads = 2 waves. Wave tile M64 x N64.
// dx loop unrolled ONLY 2x: bounds worst-case VMEM-clustered live range to
// 2 bn generations (R3 bug: unroll-16 let the scheduler keep up to 16
// 32-VGPR bn generations live -> spill -> 5.25 GB scratch writeback).
__launch_bounds__(128, 2)
__global__ void kconv(const unsigned short* __restrict__ x_t,
                      const unsigned short* __restrict__ y_t2,
                      const float* __restrict__ invn,
                      float* __restrict__ out) {
  int i = blockIdx.x;
  int n = blockIdx.y;
  int tid = threadIdx.x;
  int lane = tid & 63, wave = tid >> 6;
  int lane15 = lane & 15, q = lane >> 4;

  __shared__ __align__(16) char smem[32768];
  char* const A0 = smem;
  char* const A1 = smem + 16384;

  const char* xrow0 = (const char*)(x_t + ((size_t)(n * 128 + i)) * 8192);

  auto stageA = [&](int dy, char* buf) {
    const char* src = xrow0 + (size_t)dy * 16384;
#pragma unroll
    for (int it = 0; it < 8; ++it) {
      int chunk = it * 128 + wave * 64;  // wave-uniform LDS base
      async_g2l16(src + (chunk + lane) * 16, buf + chunk * 16);
    }
  };

  const short8* ybase = (const short8*)y_t2 + lane;
  auto loadB = [&](int t, short8 bf[4][2]) {
    const short8* p = ybase + (size_t)t * 512;  // 512 short8 per t
#pragma unroll
    for (int nt = 0; nt < 4; ++nt)
#pragma unroll
      for (int cb = 0; cb < 2; ++cb) bf[nt][cb] = p[(nt * 2 + cb) * 64];
  };

  float4v acc[4][4];
#pragma unroll
  for (int mt = 0; mt < 4; ++mt)
#pragma unroll
    for (int nt = 0; nt < 4; ++nt) acc[mt][nt] = (float4v){0.f, 0.f, 0.f, 0.f};

  int abase[4];
#pragma unroll
  for (int mt = 0; mt < 4; ++mt) abase[mt] = (wave * 64 + mt * 16 + lane15) * 128;

  stageA(0, A0);
  short8 bc[4][2];
  loadB(0, bc);
  vmem_drain();
  __syncthreads();

#pragma unroll 1
  for (int dy = 0; dy < 16; ++dy) {
    char* Ab = (dy & 1) ? A1 : A0;
    if (dy < 15) stageA(dy + 1, (dy & 1) ? A0 : A1);
#pragma unroll 2
    for (int dx = 0; dx < 16; ++dx) {
      int t = dy * 16 + dx;
      short8 bn[4][2];
      if (t < 255) loadB(t + 1, bn);
      int xr = (lane15 + dx) & 7;
#pragma unroll
      for (int cb = 0; cb < 2; ++cb) {
        int aoff = dx * 128 + (((q + cb * 4) ^ xr) << 4);
#pragma unroll
        for (int mt = 0; mt < 4; ++mt) {
          short8 a = *(const short8*)(Ab + abase[mt] + aoff);
#pragma unroll
          for (int nt = 0; nt < 4; ++nt)
            acc[mt][nt] = __builtin_amdgcn_mfma_f32_16x16x32_bf16(a, bc[nt][cb], acc[mt][nt], 0, 0, 0);
        }
      }
      if (t < 255) {
#pragma unroll
        for (int nt = 0; nt < 4; ++nt)
#pragma unroll
          for (int cb = 0; cb < 2; ++cb) bc[nt][cb] = bn[nt][cb];
      }
    }
    // Drain LDS-DMA (stageA(dy+1)) before the buffer-swap barrier (R1 bug).
    vmem_drain();
    __syncthreads();
  }

  // Epilogue: two-pass (o-halves) transpose through LDS, fuse invn + relu.
  float* cs = (float*)smem;        // 32 x 132 floats = 16896 B
  float* ivs = cs + 4224;          // 128 floats
  const float* ivp = invn + ((size_t)n * 113 + i) * 113;
  ivs[tid] = (tid < 113) ? ivp[tid] : 0.f;
  float* op = out + (size_t)n * 64 * 12769 + (size_t)i * 113;
#pragma unroll 1
  for (int p = 0; p < 2; ++p) {
#pragma unroll
    for (int mt = 0; mt < 4; ++mt)
#pragma unroll
      for (int ntl = 0; ntl < 2; ++ntl) {
        int nt = p * 2 + ntl;
        int row = ntl * 16 + lane15;          // o - p*32
        int j0 = wave * 64 + mt * 16 + q * 4;
        *(float4v*)(cs + row * 132 + j0) = acc[mt][nt];
      }
    __syncthreads();
    for (int idx = tid; idx < 4096; idx += 128) {
      int o2 = idx >> 7, j = idx & 127;
      if (j < 113) {
        float v = cs[o2 * 132 + j] * ivs[j];
        op[(size_t)(p * 32 + o2) * 12769 + j] = fmaxf(v, 0.f);
      }
    }
    __syncthreads();
  }
}

extern "C" void kernel_launch(void* const* d_in, const int* in_sizes, int n_in,
                              void* d_out, int out_size, void* d_ws, size_t ws_size,
                              hipStream_t stream) {
  const float* x = (const float*)d_in[0];
  const float* y = (const float*)d_in[1];
  float* out = (float*)d_out;
  char* ws = (char*)d_ws;
  unsigned short* x_t = (unsigned short*)ws;                 // 33,554,432 B
  unsigned short* y_t2 = (unsigned short*)(ws + 33554432);   //  2,097,152 B
  float* s = (float*)(ws + 35651584);                        //  1,048,576 B
  float* invn = (float*)(ws + 36700160);                     //    817,216 B

  hipLaunchKernelGGL(knorm_y, dim3(64), dim3(256), 0, stream, y, y_t2);
  hipLaunchKernelGGL(ktrans_x, dim3(128, 16), dim3(256), 0, stream, x, x_t, s);
  hipLaunchKernelGGL(knorm_x, dim3(113, 16), dim3(128), 0, stream, s, invn);
  hipLaunchKernelGGL(kconv, dim3(113, 16), dim3(128), 0, stream, x_t, y_t2, invn, out);
}

// Round 6
// 547.316 us; speedup vs baseline: 3.0955x; 1.2811x over previous
//
#include <hip/hip_runtime.h>
#include <stdint.h>

#define GAS __attribute__((address_space(1)))
#define LAS __attribute__((address_space(3)))

typedef __attribute__((ext_vector_type(8))) short short8;
typedef __attribute__((ext_vector_type(4))) float float4v;
typedef __attribute__((ext_vector_type(4))) unsigned int uint4v;

__device__ __forceinline__ unsigned short f2bf(float f) {
  union { float f; unsigned int u; } v; v.f = f;
  unsigned int r = v.u + 0x7fffu + ((v.u >> 16) & 1u);
  return (unsigned short)(r >> 16);
}

__device__ __forceinline__ void async_g2l16(const void* g, void* l) {
  __builtin_amdgcn_global_load_lds((const GAS unsigned int*)g,
                                   (LAS unsigned int*)l, 16, 0, 0);
}

// Full VMEM drain before s_barrier: guarantees in-flight global_load_lds
// (LDS-DMA) have landed, independent of compiler DMA tracking (R1 bug fix).
__device__ __forceinline__ void vmem_drain() {
  asm volatile("s_waitcnt vmcnt(0)" ::: "memory");
}

// ---- Kernel 1: block-specialized prep ------------------------------------
// blocks [0,2048): x (NCHW f32) -> x_t bf16 [n][h][w][c] swizzled, + s.
// blocks [2048,2112): normalize y -> bf16 fragment-major [t][og*2+cb][lane][8]:
//   for t=dy*16+dx, fragment g=(og*2+cb) is 1KB; lane = q*16+(o&15) holds
//   o = og*16+(o&15), c = cb*32 + q*8 + j (the 16x16x32 B-operand mapping).
__global__ void kprep(const float* __restrict__ x, const float* __restrict__ y,
                      unsigned short* __restrict__ x_t, unsigned short* __restrict__ y_t2,
                      float* __restrict__ s) {
  __shared__ __align__(16) unsigned short tb[8192];
  __shared__ float sb[256];
  int bx = blockIdx.x;
  int tid = threadIdx.x;
  if (bx < 2048) {
    int h = bx & 127, n = bx >> 7;
    const float* xb = x + ((size_t)n * 64) * 16384 + h * 128;
    int w = tid & 127, half = tid >> 7;
    float acc = 0.f;
#pragma unroll
    for (int cs = 0; cs < 4; ++cs) {
      short8 tmp;
#pragma unroll
      for (int j = 0; j < 8; ++j) {
        int c = half * 32 + cs * 8 + j;
        float v = xb[(size_t)c * 16384 + w];
        tmp[j] = (short)f2bf(v);
        acc += v * v;
      }
      int chunk = (half * 4 + cs) ^ (w & 7);
      *(short8*)(tb + w * 64 + chunk * 8) = tmp;
    }
    sb[tid] = acc;
    __syncthreads();
    uint4v* dst = (uint4v*)(x_t + ((size_t)(n * 128 + h)) * 8192);
    const uint4v* src = (const uint4v*)tb;
    for (int idx = tid; idx < 1024; idx += 256) dst[idx] = src[idx];
    if (tid < 128) s[((size_t)(n * 128 + h)) * 128 + tid] = sb[tid] + sb[tid + 128];
  } else {
    int o = bx - 2048;
    const float* yo = y + o * 16384;
    float sm = 0.f;
    for (int idx = tid; idx < 16384; idx += 256) { float v = yo[idx]; sm += v * v; }
    for (int off = 32; off; off >>= 1) sm += __shfl_down(sm, off, 64);
    if ((tid & 63) == 0) sb[tid >> 6] = sm;
    __syncthreads();
    float rn = 1.0f / sqrtf(sb[0] + sb[1] + sb[2] + sb[3]);
    int og = o >> 4, ol = o & 15;
    for (int idx = tid; idx < 16384; idx += 256) {
      int c = idx >> 8, dy = (idx >> 4) & 15, dx = idx & 15;
      int t = dy * 16 + dx;
      int cb = c >> 5, q = (c >> 3) & 3, j = c & 7;
      size_t dst = (size_t)t * 4096 + (size_t)(og * 2 + cb) * 512 + (q * 16 + ol) * 8 + j;
      y_t2[dst] = f2bf(yo[idx] * rn);
    }
  }
}

// ---------------- Kernel 2: main implicit-GEMM conv -----------------------
// EXACT R2 structure (known good: VGPR 60, zero spill, MfmaUtil 62%):
// block = (row i, image n), 4 waves, wave tile M64 x N32.
// A (x row) staged in LDS per dy (double-buffered, vmcnt(0)-drained barrier
// once per 16 iters). B fragments global->VGPR, pipelined one t ahead with
// bn[2][2] = 16 VGPRs per generation (32-VGPR generations spill: R3/R4).
// NEW: inv-norm computed in a prologue (separable 16x16 box sum of s through
// LDS) -> one register per thread; knorm_x launch eliminated.
__launch_bounds__(256, 3)
__global__ void kconv(const unsigned short* __restrict__ x_t,
                      const unsigned short* __restrict__ y_t2,
                      const float* __restrict__ s,
                      float* __restrict__ out) {
  int i = blockIdx.x;
  int n = blockIdx.y;
  int tid = threadIdx.x;
  int lane = tid & 63, wave = tid >> 6;
  int lane15 = lane & 15, q = lane >> 4;
  int wrow = wave >> 1, wcol = wave & 1;

  __shared__ __align__(16) char smem[32768];
  char* const A0 = smem;
  char* const A1 = smem + 16384;

  // ---- Prologue: iv = 1/||x-window|| for column j = tid & 127 ----
  float iv;
  {
    float* ps = (float*)smem;        // 256 partials, then 128 colsums at ps+256
    int col = tid & 127, half = tid >> 7;
    const float* sp = s + ((size_t)(n * 128 + i)) * 128;
    float a = 0.f;
#pragma unroll
    for (int r = 0; r < 8; ++r) a += sp[(half * 8 + r) * 128 + col];
    ps[tid] = a;
    __syncthreads();
    if (tid < 128) ps[256 + tid] = ps[tid] + ps[tid + 128];
    __syncthreads();
    float acc = 0.f;
#pragma unroll
    for (int dx = 0; dx < 16; ++dx) acc += ps[256 + col + dx];  // cols >112: garbage, unused
    iv = 1.0f / sqrtf(acc);
    __syncthreads();                 // all reads done before A-staging clobbers smem
  }

  const char* xrow0 = (const char*)(x_t + ((size_t)(n * 128 + i)) * 8192);

  auto stageA = [&](int dy, char* buf) {
    const char* src = xrow0 + (size_t)dy * 16384;
#pragma unroll
    for (int it = 0; it < 4; ++it) {
      int chunk = it * 256 + wave * 64;  // wave-uniform LDS base
      async_g2l16(src + (chunk + lane) * 16, buf + chunk * 16);
    }
  };

  const short8* ybase = (const short8*)(y_t2 + (size_t)wcol * 2048 + (size_t)lane * 8);
  auto loadB = [&](int t, short8 bf[2][2]) {
    const short8* p = ybase + (size_t)t * 512;  // 512 short8 = 4096 shorts per t
    bf[0][0] = p[0];
    bf[0][1] = p[64];
    bf[1][0] = p[128];
    bf[1][1] = p[192];
  };

  float4v acc[4][2];
#pragma unroll
  for (int mt = 0; mt < 4; ++mt)
#pragma unroll
    for (int nt = 0; nt < 2; ++nt) acc[mt][nt] = (float4v){0.f, 0.f, 0.f, 0.f};

  int abase[4];
#pragma unroll
  for (int mt = 0; mt < 4; ++mt) abase[mt] = (wrow * 64 + mt * 16 + lane15) * 128;

  stageA(0, A0);
  short8 bc[2][2];
  loadB(0, bc);
  vmem_drain();
  __syncthreads();

#pragma unroll 1
  for (int dy = 0; dy < 16; ++dy) {
    char* Ab = (dy & 1) ? A1 : A0;
    if (dy < 15) stageA(dy + 1, (dy & 1) ? A0 : A1);
#pragma unroll
    for (int dx = 0; dx < 16; ++dx) {
      int t = dy * 16 + dx;
      short8 bn[2][2];
      if (t < 255) loadB(t + 1, bn);
      int xr = (lane15 + dx) & 7;
#pragma unroll
      for (int cb = 0; cb < 2; ++cb) {
        int aoff = dx * 128 + (((q + cb * 4) ^ xr) << 4);
#pragma unroll
        for (int mt = 0; mt < 4; ++mt) {
          short8 a = *(const short8*)(Ab + abase[mt] + aoff);
          acc[mt][0] = __builtin_amdgcn_mfma_f32_16x16x32_bf16(a, bc[0][cb], acc[mt][0], 0, 0, 0);
          acc[mt][1] = __builtin_amdgcn_mfma_f32_16x16x32_bf16(a, bc[1][cb], acc[mt][1], 0, 0, 0);
        }
      }
      if (t < 255) {
        bc[0][0] = bn[0][0]; bc[0][1] = bn[0][1];
        bc[1][0] = bn[1][0]; bc[1][1] = bn[1][1];
      }
    }
    // Drain LDS-DMA (stageA(dy+1)) before the buffer-swap barrier (R1 bug).
    vmem_drain();
    __syncthreads();
  }

  // Epilogue: two-pass (o-halves) transpose through LDS, fuse iv + relu.
  float* cs = (float*)smem;        // 32 x 132 floats = 16896 B
  float* op = out + (size_t)n * 64 * 12769 + (size_t)i * 113;
#pragma unroll 1
  for (int p = 0; p < 2; ++p) {
    if (wcol == p) {
#pragma unroll
      for (int mt = 0; mt < 4; ++mt)
#pragma unroll
        for (int nt = 0; nt < 2; ++nt) {
          int row = nt * 16 + lane15;          // o - p*32
          int j0 = wrow * 64 + mt * 16 + q * 4;
          *(float4v*)(cs + row * 132 + j0) = acc[mt][nt];
        }
    }
    __syncthreads();
    for (int idx = tid; idx < 4096; idx += 256) {
      int o2 = idx >> 7, j = idx & 127;        // j == tid & 127, matches iv
      if (j < 113) {
        float v = cs[o2 * 132 + j] * iv;
        op[(size_t)(p * 32 + o2) * 12769 + j] = fmaxf(v, 0.f);
      }
    }
    __syncthreads();
  }
}

extern "C" void kernel_launch(void* const* d_in, const int* in_sizes, int n_in,
                              void* d_out, int out_size, void* d_ws, size_t ws_size,
                              hipStream_t stream) {
  const float* x = (const float*)d_in[0];
  const float* y = (const float*)d_in[1];
  float* out = (float*)d_out;
  char* ws = (char*)d_ws;
  unsigned short* x_t = (unsigned short*)ws;                 // 33,554,432 B
  unsigned short* y_t2 = (unsigned short*)(ws + 33554432);   //  2,097,152 B
  float* s = (float*)(ws + 35651584);                        //  1,048,576 B

  hipLaunchKernelGGL(kprep, dim3(2112), dim3(256), 0, stream, x, y, x_t, y_t2, s);
  hipLaunchKernelGGL(kconv, dim3(113, 16), dim3(256), 0, stream, x_t, y_t2, s, out);
}